// Round 2
// baseline (718.188 us; speedup 1.0000x reference)
//
#include <hip/hip_runtime.h>
#include <math.h>

#define NN 20000
#define NN_PAD 20096   // NN rounded up to TM; pad rows are garbage, never stored
#define EE 320000
#define RR 3
#define LL 3
#define HH 4
#define DD 64
#define CDIM 256   // H*D == IN
#define OUTD 128
#define NEG 0.2f

typedef float f32x4 __attribute__((ext_vector_type(4)));
typedef short sh8 __attribute__((ext_vector_type(8)));

__device__ __forceinline__ ushort f2bf(float f) {
    union { float f; uint u; } v; v.f = f;
    uint r = (v.u + 0x7FFF + ((v.u >> 16) & 1)) >> 16;   // RNE
    return (ushort)r;
}
__device__ __forceinline__ float bf2f(ushort u) {
    union { uint u; float f; } v; v.u = ((uint)u) << 16;
    return v.f;
}
__device__ __forceinline__ float bflo(uint p) { return bf2f((ushort)(p & 0xffff)); }
__device__ __forceinline__ float bfhi(uint p) { return bf2f((ushort)(p >> 16)); }

// async global->LDS, 16 B per lane; LDS dst is wave-uniform base + lane*16
__device__ __forceinline__ void glds16(const ushort* g, ushort* l) {
    __builtin_amdgcn_global_load_lds(
        (const __attribute__((address_space(1))) void*)g,
        (__attribute__((address_space(3))) void*)l, 16, 0, 0);
}

// ---------------- CSR build ----------------

__global__ void count_deg(const int* __restrict__ edge_dst, int* __restrict__ deg) {
    int i = blockIdx.x * blockDim.x + threadIdx.x;
    if (i >= RR * EE) return;
    int r = i / EE;
    atomicAdd(&deg[r * NN + edge_dst[i]], 1);
}

// one block per relation; wave-shfl scan; writes row_ptr AND cursor copy.
__global__ __launch_bounds__(1024) void scan_kernel(
    const int* __restrict__ deg, int* __restrict__ row_ptr, int* __restrict__ cursor) {
    int r = blockIdx.x;
    const int* d = deg + r * NN;
    int* rp = row_ptr + r * (NN + 1);
    int* cur = cursor + r * (NN + 1);
    __shared__ int wsum[16];
    int lane = threadIdx.x & 63, wv = threadIdx.x >> 6;
    if (threadIdx.x == 0) { rp[0] = 0; cur[0] = 0; }
    int carry = 0;
    for (int base = 0; base < NN; base += 1024) {
        int i = base + threadIdx.x;
        int v = (i < NN) ? d[i] : 0;
        int s = v;
        #pragma unroll
        for (int off = 1; off < 64; off <<= 1) {
            int n = __shfl_up(s, off, 64);
            if (lane >= off) s += n;
        }
        if (lane == 63) wsum[wv] = s;
        __syncthreads();
        if (wv == 0) {
            int ws = (lane < 16) ? wsum[lane] : 0;
            #pragma unroll
            for (int off = 1; off < 16; off <<= 1) {
                int n = __shfl_up(ws, off, 64);
                if (lane >= off) ws += n;
            }
            if (lane < 16) wsum[lane] = ws;
        }
        __syncthreads();
        int incl = carry + (wv ? wsum[wv - 1] : 0) + s;
        if (i < NN) { rp[i + 1] = incl; cur[i + 1] = incl; }
        carry += wsum[15];
        __syncthreads();
    }
}

// cursor[] starts as a copy of row_ptr; atomically bump to place each edge.
__global__ void fill_csr(const int* __restrict__ edge_src, const int* __restrict__ edge_dst,
                         int* __restrict__ cursor, int* __restrict__ csr_src) {
    int i = blockIdx.x * blockDim.x + threadIdx.x;
    if (i >= RR * EE) return;
    int r = i / EE;
    int dst = edge_dst[i];
    int pos = atomicAdd(&cursor[r * (NN + 1) + dst], 1);
    csr_src[r * EE + pos] = edge_src[i];
}

// ---------------- dtype prep ----------------

__global__ void cvt_bf16x4(const float* __restrict__ in, ushort* __restrict__ out, int n4) {
    int i = blockIdx.x * blockDim.x + threadIdx.x;
    if (i >= n4) return;
    float4 v = *(const float4*)(in + (size_t)i * 4);
    ushort4 o;
    o.x = f2bf(v.x); o.y = f2bf(v.y); o.z = f2bf(v.z); o.w = f2bf(v.w);
    *(ushort4*)(out + (size_t)i * 4) = o;
}

// transpose fp32 [K][N] -> bf16 [N][K]; z<LL*RR: W matrices; z==LL*RR: fc_w.
__global__ void prep_all(const float* __restrict__ W, const float* __restrict__ fc_w,
                         ushort* __restrict__ Wt, ushort* __restrict__ fct) {
    __shared__ float tile[32][33];
    int z = blockIdx.z;
    const float* src;
    ushort* dst;
    int N;
    if (z < LL * RR) {
        src = W + (size_t)z * CDIM * CDIM;
        dst = Wt + (size_t)z * CDIM * CDIM;
        N = CDIM;
    } else {
        src = fc_w;
        dst = fct;
        N = OUTD;
    }
    int kb = blockIdx.x * 32, nb = blockIdx.y * 32;
    if (nb >= N) return;
    for (int yy = threadIdx.y; yy < 32; yy += 8)
        tile[yy][threadIdx.x] = src[(size_t)(kb + yy) * N + nb + threadIdx.x];
    __syncthreads();
    for (int yy = threadIdx.y; yy < 32; yy += 8)
        dst[(size_t)(nb + yy) * CDIM + kb + threadIdx.x] = f2bf(tile[threadIdx.x][yy]);
}

// ---------------- bf16 MFMA GEMM (+ fused el/er epilogue) ----------------
// C[M][Ncol] = A[M][K](bf16) @ Bt[Ncol][K](bf16)^T ; 128x128 tile, BK=32.

#define TM 128
#define TN 128
#define TK 32

__global__ __launch_bounds__(256) void gemm_bf16(
    const ushort* __restrict__ A, const ushort* __restrict__ Bt0, void* __restrict__ C0,
    int M, int K, int Ncol, long strideB, long strideC,
    const float* __restrict__ bias, int out_fp32,
    const float* __restrict__ al_all, const float* __restrict__ ar_all,
    float* __restrict__ el_all, float* __restrict__ er_all) {
    __shared__ alignas(16) ushort As[TM * 32];
    __shared__ alignas(16) ushort Bs[TN * 32];
    const ushort* Bt = Bt0 + (size_t)blockIdx.z * strideB;
    int m0 = blockIdx.x * TM, n0 = blockIdx.y * TN;
    int t = threadIdx.x;
    int wave = t >> 6, lane = t & 63;
    int q = lane >> 4, l16 = lane & 15;
    int wrow = (wave >> 1) * 64, wcol = (wave & 1) * 64;

    // fragment LDS offsets (shorts), k0-independent; chunk swizzle = q ^ ((l16>>1)&3)
    int sw = (q ^ ((l16 >> 1) & 3)) * 8;
    int a_off[4], b_off[4];
    #pragma unroll
    for (int i = 0; i < 4; i++) {
        a_off[i] = (wrow + i * 16 + l16) * 32 + sw;
        b_off[i] = (wcol + i * 16 + l16) * 32 + sw;
    }
    // staging: qid in [0,512): row = qid>>2, global chunk = (qid&3) ^ ((row>>1)&3)
    int row_a = t >> 2;
    int ch_a  = ((t & 3) ^ ((row_a >> 1) & 3)) * 8;

    f32x4 acc[4][4];
    #pragma unroll
    for (int i = 0; i < 4; i++)
        #pragma unroll
        for (int j = 0; j < 4; j++)
            #pragma unroll
            for (int k = 0; k < 4; k++) acc[i][j][k] = 0.f;

    for (int k0 = 0; k0 < K; k0 += TK) {
        #pragma unroll
        for (int s = 0; s < 2; s++) {
            int qid = t + s * 256;
            int row = row_a + s * 64;
            glds16(A + (size_t)(m0 + row) * K + k0 + ch_a, As + qid * 8);
        }
        #pragma unroll
        for (int s = 0; s < 2; s++) {
            int qid = t + s * 256;
            int row = row_a + s * 64;
            glds16(Bt + (size_t)(n0 + row) * K + k0 + ch_a, Bs + qid * 8);
        }
        __syncthreads();
        sh8 af[4], bfr[4];
        #pragma unroll
        for (int i = 0; i < 4; i++) af[i] = *(const sh8*)(As + a_off[i]);
        #pragma unroll
        for (int j = 0; j < 4; j++) bfr[j] = *(const sh8*)(Bs + b_off[j]);
        #pragma unroll
        for (int i = 0; i < 4; i++)
            #pragma unroll
            for (int j = 0; j < 4; j++)
                acc[i][j] = __builtin_amdgcn_mfma_f32_16x16x32_bf16(af[i], bfr[j], acc[i][j], 0, 0, 0);
        __syncthreads();
    }

    // epilogue: C/D layout col=lane&15, row=q*4+reg
    if (out_fp32) {
        float* C = (float*)C0 + (size_t)blockIdx.z * strideC;
        #pragma unroll
        for (int i = 0; i < 4; i++) {
            #pragma unroll
            for (int reg = 0; reg < 4; reg++) {
                int row = m0 + wrow + i * 16 + q * 4 + reg;
                if (row >= M) continue;
                #pragma unroll
                for (int j = 0; j < 4; j++) {
                    int col = n0 + wcol + j * 16 + l16;
                    float v = acc[i][j][reg];
                    if (bias) v += bias[col];
                    C[(size_t)row * Ncol + col] = v;
                }
            }
        }
    } else {
        ushort* C = (ushort*)C0 + (size_t)blockIdx.z * strideC;
        #pragma unroll
        for (int i = 0; i < 4; i++) {
            #pragma unroll
            for (int reg = 0; reg < 4; reg++) {
                int row = m0 + wrow + i * 16 + q * 4 + reg;
                if (row >= M) continue;
                #pragma unroll
                for (int j = 0; j < 4; j++) {
                    int col = n0 + wcol + j * 16 + l16;
                    C[(size_t)row * Ncol + col] = f2bf(acc[i][j][reg]);
                }
            }
        }
    }

    if (el_all) {
        const float* al = al_all + (size_t)blockIdx.z * CDIM;
        const float* ar = ar_all + (size_t)blockIdx.z * CDIM;
        float* elp = el_all + (size_t)blockIdx.z * NN * HH;
        float* erp = er_all + (size_t)blockIdx.z * NN * HH;
        int head = (n0 + wcol) >> 6;
        float alj[4], arj[4];
        #pragma unroll
        for (int j = 0; j < 4; j++) {
            int gcol = n0 + wcol + j * 16 + l16;
            alj[j] = al[gcol];
            arj[j] = ar[gcol];
        }
        #pragma unroll
        for (int i = 0; i < 4; i++) {
            #pragma unroll
            for (int reg = 0; reg < 4; reg++) {
                int row = m0 + wrow + i * 16 + q * 4 + reg;
                float pl = 0.f, pr = 0.f;
                #pragma unroll
                for (int j = 0; j < 4; j++) {
                    pl = fmaf(acc[i][j][reg], alj[j], pl);
                    pr = fmaf(acc[i][j][reg], arj[j], pr);
                }
                #pragma unroll
                for (int m = 1; m < 16; m <<= 1) {
                    pl += __shfl_xor(pl, m, 64);
                    pr += __shfl_xor(pr, m, 64);
                }
                if (l16 == 0 && row < M) {
                    elp[(size_t)row * HH + head] = pl;
                    erp[(size_t)row * HH + head] = pr;
                }
            }
        }
    }
}

// ---------------- pass 1: unnormalized attention weights (bf16) ----------------
// wave per node; lane = head(4) x edge-slot(16). Writes A[r][h][e] =
// bf16(exp(lrelu(el[src,h] + er[node,h]))) in CSR order (head-major so pass
// 2's per-chunk stream is dense). el table is 960 KB -> L2-resident gathers.
// bf16 is safe here: fp32 exponent range (no overflow, unlike fp16), and
// pass 2 normalizes by the sum of the SAME quantized values, so common-mode
// quantization error cancels (per-alpha rel err ~2^-9).
__global__ __launch_bounds__(256) void attn_alpha(
    const float* __restrict__ el, const float* __restrict__ er,
    const int* __restrict__ row_ptr, const int* __restrict__ csr_src,
    ushort* __restrict__ A) {
    int wv = threadIdx.x >> 6, lane = threadIdx.x & 63;
    int node = blockIdx.x * 4 + wv;
    if (node >= NN) return;
    int h = lane >> 4, jj = lane & 15;
    #pragma unroll
    for (int r = 0; r < RR; r++) {
        const int* rp = row_ptr + r * (NN + 1);
        int beg = rp[node], end = rp[node + 1];
        const int* cs = csr_src + (size_t)r * EE;
        const float* elr = el + (size_t)r * NN * HH;
        float ern = er[((size_t)r * NN + node) * HH + h];
        ushort* Ar = A + ((size_t)(r * HH + h)) * EE;
        for (int e = beg + jj; e < end; e += 16) {
            int s = cs[e];
            float x = elr[(size_t)s * HH + h] + ern;
            x = x > 0.f ? x : NEG * x;
            Ar[e] = f2bf(__expf(x));
        }
    }
}

// ---------------- pass 2: chunked weighted gather (XCD-local L2) ----------------
// Output channel dim split into 4 head-chunks of 64 ch (128 B of a feat row).
// chunk = (bid&7)>>1: with round-robin block->XCD dispatch, each chunk's
// blocks land on 2 XCDs, whose private L2 then only holds a 2.56 MB/relation
// slice of feat16 -> compulsory fetch drops ~4x vs full-row gathers.
// Wave = one (node, chunk); lane = j(2 edges in flight) x c(32 channel-pairs):
// each half-wave reads exactly one 128 B line per edge. A[] streams in CSR
// order (2B broadcast loads); sum(A) accumulated inline; per-relation 1/sum
// applied before the cross-half reduce (uniform scale commutes).
__global__ __launch_bounds__(256) void agg_pass2(
    const ushort* __restrict__ feat16, const ushort* __restrict__ A,
    const int* __restrict__ row_ptr, const int* __restrict__ csr_src,
    const float* __restrict__ bias, ushort* __restrict__ hout, int relu) {
    int bid = blockIdx.x;
    int chunk = (bid & 7) >> 1;          // head 0..3 -> XCD pair
    int par = bid & 1;
    int grp = bid >> 3;
    int wv = threadIdx.x >> 6, lane = threadIdx.x & 63;
    int node = grp * 8 + par * 4 + wv;   // NN = 2500*8 exactly
    if (node >= NN) return;
    int h = chunk;
    int j = lane >> 5, c = lane & 31;
    int ch = h * 64 + 2 * c;             // ushort index within feat row

    float t0 = 0.f, t1 = 0.f;
    #pragma unroll
    for (int r = 0; r < RR; r++) {
        const int* rp = row_ptr + r * (NN + 1);
        int beg = rp[node], end = rp[node + 1];
        const int* cs = csr_src + (size_t)r * EE;
        const ushort* Ar = A + ((size_t)(r * HH + h)) * EE;
        const ushort* fr = feat16 + (size_t)r * NN * CDIM;
        float p0 = 0.f, p1 = 0.f, ss = 0.f;
        int e = beg + j;
        if (e < end) {
            int s = cs[e];
            float a = bf2f(Ar[e]);
            for (e += 2; e < end; e += 2) {
                int sn = cs[e];
                float an = bf2f(Ar[e]);
                uint f = *(const uint*)(fr + (size_t)s * CDIM + ch);
                ss += a;
                p0 = fmaf(a, bflo(f), p0);
                p1 = fmaf(a, bfhi(f), p1);
                s = sn; a = an;
            }
            uint f = *(const uint*)(fr + (size_t)s * CDIM + ch);
            ss += a;
            p0 = fmaf(a, bflo(f), p0);
            p1 = fmaf(a, bfhi(f), p1);
        }
        ss += __shfl_xor(ss, 32, 64);                  // total sum over node's edges
        float is = (end > beg) ? 1.f / ss : 0.f;
        t0 = fmaf(p0, is, t0);
        t1 = fmaf(p1, is, t1);
        float2 b = *(const float2*)(bias + r * CDIM + ch);
        t0 += 0.5f * b.x;                              // bias added by BOTH halves,
        t1 += 0.5f * b.y;                              // halved so post-reduce sum is 1x
    }
    t0 += __shfl_xor(t0, 32, 64);
    t1 += __shfl_xor(t1, 32, 64);
    if (relu) { t0 = fmaxf(t0, 0.f); t1 = fmaxf(t1, 0.f); }
    if (j == 0) {
        uint o = (uint)f2bf(t0) | ((uint)f2bf(t1) << 16);
        *(uint*)(hout + (size_t)node * CDIM + ch) = o;
    }
}

// ---------------- launcher ----------------

extern "C" void kernel_launch(void* const* d_in, const int* in_sizes, int n_in,
                              void* d_out, int out_size, void* d_ws, size_t ws_size,
                              hipStream_t stream) {
    const float* x        = (const float*)d_in[0];
    const int*   edge_src = (const int*)d_in[1];
    const int*   edge_dst = (const int*)d_in[2];
    const float* W        = (const float*)d_in[3];
    const float* attn_l   = (const float*)d_in[4];
    const float* attn_r   = (const float*)d_in[5];
    const float* bias     = (const float*)d_in[6];
    const float* fc_w     = (const float*)d_in[7];
    const float* fc_b     = (const float*)d_in[8];
    float* out = (float*)d_out;

    char* ws = (char*)d_ws;
    size_t off = 0;
    auto alloc = [&](size_t bytes) {
        void* p = ws + off;
        off = (off + bytes + 255) & ~(size_t)255;
        return p;
    };
    ushort* x16    = (ushort*)alloc((size_t)NN_PAD * CDIM * 2);  // padded: glds A-source
    ushort* h16    = (ushort*)alloc((size_t)NN_PAD * CDIM * 2);  // padded: glds A-source
    ushort* feat16 = (ushort*)alloc((size_t)RR * NN * CDIM * 2);
    ushort* Wt16   = (ushort*)alloc((size_t)LL * RR * CDIM * CDIM * 2);
    ushort* fct16  = (ushort*)alloc((size_t)OUTD * CDIM * 2);
    float* el      = (float*)alloc((size_t)RR * NN * HH * 4);
    float* er      = (float*)alloc((size_t)RR * NN * HH * 4);
    int* row_ptr   = (int*)alloc((size_t)RR * (NN + 1) * 4);
    int* cursor    = (int*)alloc((size_t)RR * (NN + 1) * 4);
    int* csr_src   = (int*)alloc((size_t)RR * EE * 4);
    int* deg       = (int*)alloc((size_t)RR * NN * 4);
    // Aw (bf16, [r][h][e], 7.68 MB) ALIASES x16 (10.29 MB): x16 is dead after
    // the layer-0 GEMM, and attn_alpha (first Aw writer) launches after it on
    // the same stream. Keeps total workspace at the previously-proven footprint.
    ushort* Aw = x16;

    // CSR build
    hipMemsetAsync(deg, 0, (size_t)RR * NN * 4, stream);
    count_deg<<<dim3((RR * EE + 255) / 256), dim3(256), 0, stream>>>(edge_dst, deg);
    scan_kernel<<<dim3(RR), dim3(1024), 0, stream>>>(deg, row_ptr, cursor);
    fill_csr<<<dim3((RR * EE + 255) / 256), dim3(256), 0, stream>>>(
        edge_src, edge_dst, cursor, csr_src);

    // dtype prep
    cvt_bf16x4<<<dim3((NN * CDIM / 4 + 255) / 256), dim3(256), 0, stream>>>(x, x16, NN * CDIM / 4);
    prep_all<<<dim3(CDIM / 32, CDIM / 32, LL * RR + 1), dim3(32, 8), 0, stream>>>(
        W, fc_w, Wt16, fct16);

    const ushort* hin = x16;
    for (int l = 0; l < LL; l++) {
        const ushort* Wl = Wt16 + (size_t)l * RR * CDIM * CDIM;
        dim3 g(NN_PAD / TM, CDIM / TN, RR);
        gemm_bf16<<<g, dim3(256), 0, stream>>>(hin, Wl, feat16, NN, CDIM, CDIM,
                                               (long)CDIM * CDIM, (long)NN * CDIM, nullptr, 0,
                                               attn_l + (size_t)l * RR * CDIM,
                                               attn_r + (size_t)l * RR * CDIM, el, er);
        attn_alpha<<<dim3(NN / 4), dim3(256), 0, stream>>>(el, er, row_ptr, csr_src, Aw);
        agg_pass2<<<dim3(NN), dim3(256), 0, stream>>>(
            feat16, Aw, row_ptr, csr_src, bias + (size_t)l * RR * CDIM,
            h16, (l != LL - 1) ? 1 : 0);
        hin = h16;
    }
    dim3 gf(NN_PAD / TM, OUTD / TN, 1);
    gemm_bf16<<<gf, dim3(256), 0, stream>>>(h16, fct16, out, NN, CDIM, OUTD,
                                            0, 0, fc_b, 1, nullptr, nullptr, nullptr, nullptr);
}